// Round 16
// baseline (257.877 us; speedup 1.0000x reference)
//
#include <hip/hip_runtime.h>

#define NN 50000
#define NE 800000
#define F  64
#define NBKT 196              // dst>>8 buckets (max dst 49999 -> 195)
#define CHUNK (NE / 256)      // 3125 edges per sort block

typedef __attribute__((ext_vector_type(8))) short bf16x8;
typedef __attribute__((ext_vector_type(4))) float f32x4;

// ---- workspace layout (bytes), 256-aligned ----
#define WS_FLAG   0u
#define WS_WCTH   256u        // 3*128*64 u16: [A|B]^T hi    -> 49408
#define WS_WCTL   49408u      // 3*128*64 u16: [A|B]^T lo    -> 98560
#define WS_W2TH   98560u      // 3*4096 u16 (bf16 hi of W2T) -> 123136
#define WS_W2TL   123136u     // 3*4096 u16 (bf16 lo of W2T) -> 147712
#define WS_SEDGE  147712u     // NE u32 packed (dst<<16)|src -> 3347712
#define WS_U      3347712u    // NN*F f32                    -> 16147712
#define WS_V      16147712u   // NN*F f32                    -> 28947712
// sort scratch aliased inside U/V (sort completes before first gemm writes them)
#define WS_BHT    (WS_U + 0u)        // NBKT*256 int (transposed block hists)
#define WS_BOT    (WS_U + 200960u)   // NBKT*256 int (per-block bucket offsets)
#define WS_CSUM   (WS_U + 401920u)   // NBKT int (bucket totals)
#define WS_BASE   (WS_U + 402944u)   // NBKT int (bucket bases)
#define WS_TMP    (WS_V + 0u)        // NE u32  coarse-bucketed edges

__device__ __forceinline__ float relu_f(float a) { return a > 0.f ? a : 0.f; }

// pack 4 floats into 2 hi-bf16 words + 2 lo-bf16 words.
// v_perm_b32 fuses the truncate+combine: hw = h1|(h0>>16) = byte-select
// [u0.b2,u0.b3,u1.b2,u1.b3] = perm(u1,u0,0x07060302). Bit-exact vs shift/or.
__device__ __forceinline__ void pack4(float f0, float f1, float f2, float f3,
                                      unsigned& hw0, unsigned& hw1,
                                      unsigned& lw0, unsigned& lw1) {
    unsigned u0 = __float_as_uint(f0), u1 = __float_as_uint(f1);
    unsigned u2 = __float_as_uint(f2), u3 = __float_as_uint(f3);
    hw0 = __builtin_amdgcn_perm(u1, u0, 0x07060302u);
    hw1 = __builtin_amdgcn_perm(u3, u2, 0x07060302u);
    float l0 = f0 - __uint_as_float(u0 & 0xffff0000u);
    float l1 = f1 - __uint_as_float(u1 & 0xffff0000u);
    float l2 = f2 - __uint_as_float(u2 & 0xffff0000u);
    float l3 = f3 - __uint_as_float(u3 & 0xffff0000u);
    lw0 = __builtin_amdgcn_perm(__float_as_uint(l1), __float_as_uint(l0), 0x07060302u);
    lw1 = __builtin_amdgcn_perm(__float_as_uint(l3), __float_as_uint(l2), 0x07060302u);
}

// --- detect idx payload: int64 (odd words all zero) vs int32 ---
__global__ void detect_kernel(const int* __restrict__ idx, int* __restrict__ flag) {
    int t = blockIdx.x * blockDim.x + threadIdx.x;   // 4096 samples
    if (idx[2 * t + 1] != 0) atomicOr(flag, 1);      // 1 -> int32 layout
}

// --- build transposed hi/lo bf16 splits: WC = [A|B] (A = W1a - W1b, B = W1b), W2T ---
__global__ void prep_kernel(const float* __restrict__ W1, const float* __restrict__ W2,
                            unsigned short* __restrict__ WCTH, unsigned short* __restrict__ WCTL,
                            unsigned short* __restrict__ W2TH, unsigned short* __restrict__ W2TL) {
    int i = blockIdx.x * blockDim.x + threadIdx.x;   // 0 .. 3*4096-1
    int l = i >> 12;
    int r = i & 4095;
    int k = r >> 6;
    int j = r & 63;
    float wa = W1[l * 8192 + k * 64 + j];
    float wb = W1[l * 8192 + 4096 + k * 64 + j];
    float a = wa - wb;
    unsigned ua = __float_as_uint(a), ahi = ua & 0xffff0000u;
    float alo = a - __uint_as_float(ahi);
    WCTH[l * 8192 + j * 64 + k] = (unsigned short)(ahi >> 16);
    WCTL[l * 8192 + j * 64 + k] = (unsigned short)(__float_as_uint(alo) >> 16);
    unsigned ub = __float_as_uint(wb), bhi = ub & 0xffff0000u;
    float blo = wb - __uint_as_float(bhi);
    WCTH[l * 8192 + (64 + j) * 64 + k] = (unsigned short)(bhi >> 16);
    WCTL[l * 8192 + (64 + j) * 64 + k] = (unsigned short)(__float_as_uint(blo) >> 16);
    float w = W2[l * 4096 + k * 64 + j];
    unsigned uw = __float_as_uint(w), whi = uw & 0xffff0000u;
    float wlo = w - __uint_as_float(whi);
    W2TH[l * 4096 + j * 64 + k] = (unsigned short)(whi >> 16);
    W2TL[l * 4096 + j * 64 + k] = (unsigned short)(__float_as_uint(wlo) >> 16);
}

// --- MFMA gemm: [U|V] = x @ [A|B] (+b1 on U). Wave = (64-node batch) x (U or V half). ---
__global__ __launch_bounds__(256, 2) void gemm_mfma(
    const float* __restrict__ xin,
    const unsigned short* __restrict__ WCTH, const unsigned short* __restrict__ WCTL,
    const float* __restrict__ b1,
    float* __restrict__ U, float* __restrict__ V) {
    __shared__ char smem[65536];                 // 4 waves x 16 KB, wave-private
    int lane = threadIdx.x & 63;
    int wib  = threadIdx.x >> 6;
    char* base = smem + wib * 16384;
    char* Hhi = base;
    char* Hlo = base + 8192;
    int l15 = lane & 15, l4 = lane >> 4;

    int wid = blockIdx.x * 4 + wib;              // 1564 waves exactly
    int b = wid >> 1;                            // node batch (0..781)
    int half = wid & 1;                          // 0 -> U, 1 -> V

    bf16x8 Bh[2][4], Bl[2][4];
#pragma unroll
    for (int kt = 0; kt < 2; ++kt)
#pragma unroll
        for (int nt = 0; nt < 4; ++nt) {
            int off = (half * 64 + nt * 16 + l15) * 64 + kt * 32 + l4 * 8;
            Bh[kt][nt] = *(const bf16x8*)(WCTH + off);
            Bl[kt][nt] = *(const bf16x8*)(WCTL + off);
        }

    int jj = lane & 15;                          // float4 chunk within row
    int rsub = lane >> 4;                        // row sub-index within group of 4
#pragma unroll
    for (int i = 0; i < 16; ++i) {
        int r = 4 * i + rsub;
        int node = b * 64 + r;
        int cnode = node < NN ? node : NN - 1;
        float4 xv = *(const float4*)(xin + (size_t)cnode * F + 4 * jj);
        unsigned hw0, hw1, lw0, lw1;
        pack4(xv.x, xv.y, xv.z, xv.w, hw0, hw1, lw0, lw1);
        int g = jj >> 1;
        int byt = r * 128 + ((g ^ (r & 7)) << 4) + (jj & 1) * 8;
        *(uint2*)(Hhi + byt) = make_uint2(hw0, hw1);
        *(uint2*)(Hlo + byt) = make_uint2(lw0, lw1);
    }

    f32x4 acc[4][4];
#pragma unroll
    for (int mt = 0; mt < 4; ++mt)
#pragma unroll
        for (int nt = 0; nt < 4; ++nt)
            acc[mt][nt] = (f32x4){0.f, 0.f, 0.f, 0.f};
#pragma unroll
    for (int mt = 0; mt < 4; ++mt) {
        int arow = mt * 16 + l15;
        int abase = arow * 128;
        int am = arow & 7;
        bf16x8 Ah0 = *(const bf16x8*)(Hhi + abase + (((0 + l4) ^ am) << 4));
        bf16x8 Ah1 = *(const bf16x8*)(Hhi + abase + (((4 + l4) ^ am) << 4));
        bf16x8 Al0 = *(const bf16x8*)(Hlo + abase + (((0 + l4) ^ am) << 4));
        bf16x8 Al1 = *(const bf16x8*)(Hlo + abase + (((4 + l4) ^ am) << 4));
#pragma unroll
        for (int nt = 0; nt < 4; ++nt) {
            f32x4 a = acc[mt][nt];
            a = __builtin_amdgcn_mfma_f32_16x16x32_bf16(Ah0, Bh[0][nt], a, 0, 0, 0);
            a = __builtin_amdgcn_mfma_f32_16x16x32_bf16(Ah1, Bh[1][nt], a, 0, 0, 0);
            a = __builtin_amdgcn_mfma_f32_16x16x32_bf16(Al0, Bh[0][nt], a, 0, 0, 0);
            a = __builtin_amdgcn_mfma_f32_16x16x32_bf16(Al1, Bh[1][nt], a, 0, 0, 0);
            a = __builtin_amdgcn_mfma_f32_16x16x32_bf16(Ah0, Bl[0][nt], a, 0, 0, 0);
            a = __builtin_amdgcn_mfma_f32_16x16x32_bf16(Ah1, Bl[1][nt], a, 0, 0, 0);
            acc[mt][nt] = a;
        }
    }

    float bc[4];
#pragma unroll
    for (int nt = 0; nt < 4; ++nt)
        bc[nt] = (half == 0) ? b1[nt * 16 + l15] : 0.f;
    float* outp = (half == 0) ? U : V;
#pragma unroll
    for (int mt = 0; mt < 4; ++mt)
#pragma unroll
        for (int nt = 0; nt < 4; ++nt) {
            int col = nt * 16 + l15;
#pragma unroll
            for (int r = 0; r < 4; ++r) {
                int row = b * 64 + mt * 16 + l4 * 4 + r;
                if (row < NN) outp[(size_t)row * F + col] = acc[mt][nt][r] + bc[nt];
            }
        }
}

// --- deterministic split-sort by dst: NO global atomics anywhere ---
__global__ __launch_bounds__(256) void histA_kernel(const int* __restrict__ idx,
                                                    const int* __restrict__ flag,
                                                    int* __restrict__ bhistT) {
    __shared__ int h[NBKT];
    int tid = threadIdx.x, blk = blockIdx.x;
    if (tid < NBKT) h[tid] = 0;
    __syncthreads();
    int fl = *flag;
    int start = blk * CHUNK;
    for (int i = tid; i < CHUNK; i += 256) {
        int e = start + i;
        int dst = fl ? idx[NE + e] : idx[2 * NE + 2 * e];
        atomicAdd(&h[dst >> 8], 1);
    }
    __syncthreads();
    if (tid < NBKT) bhistT[tid * 256 + blk] = h[tid];
}

__global__ __launch_bounds__(256) void scanCols_kernel(const int* __restrict__ bhistT,
                                                       int* __restrict__ boffT,
                                                       int* __restrict__ csum) {
    __shared__ int buf[256];
    int t = threadIdx.x, b = blockIdx.x;
    int v = bhistT[b * 256 + t];
    buf[t] = v;
    __syncthreads();
    for (int d = 1; d < 256; d <<= 1) {
        int add = (t >= d) ? buf[t - d] : 0;
        __syncthreads();
        buf[t] += add;
        __syncthreads();
    }
    boffT[b * 256 + t] = buf[t] - v;
    if (t == 255) csum[b] = buf[255];
}

__global__ __launch_bounds__(256) void scanBase_kernel(const int* __restrict__ csum,
                                                       int* __restrict__ base) {
    __shared__ int buf[256];
    int t = threadIdx.x;
    int v = (t < NBKT) ? csum[t] : 0;
    buf[t] = v;
    __syncthreads();
    for (int d = 1; d < 256; d <<= 1) {
        int add = (t >= d) ? buf[t - d] : 0;
        __syncthreads();
        buf[t] += add;
        __syncthreads();
    }
    if (t < NBKT) base[t] = buf[t] - v;
}

__global__ __launch_bounds__(256) void scatterA2_kernel(const int* __restrict__ idx,
                                                        const int* __restrict__ flag,
                                                        const int* __restrict__ boffT,
                                                        const int* __restrict__ base,
                                                        unsigned* __restrict__ tmp) {
    __shared__ int loc[NBKT];
    __shared__ int bb[NBKT];
    int tid = threadIdx.x, blk = blockIdx.x;
    if (tid < NBKT) { loc[tid] = 0; bb[tid] = base[tid] + boffT[tid * 256 + blk]; }
    __syncthreads();
    int fl = *flag;
    int start = blk * CHUNK;
    for (int i = tid; i < CHUNK; i += 256) {
        int e = start + i;
        int src, dst;
        if (fl) { src = idx[e];     dst = idx[NE + e]; }
        else    { src = idx[2 * e]; dst = idx[2 * NE + 2 * e]; }
        int bkt = dst >> 8;
        int my = atomicAdd(&loc[bkt], 1);          // LDS only
        tmp[bb[bkt] + my] = ((unsigned)dst << 16) | (unsigned)src;
    }
}

__global__ __launch_bounds__(256) void sortC_kernel(const unsigned* __restrict__ tmp,
                                                    const int* __restrict__ base,
                                                    const int* __restrict__ csum,
                                                    unsigned* __restrict__ sedge) {
    __shared__ int cnt[256];
    __shared__ int pos[256];
    int b = blockIdx.x, t = threadIdx.x;
    int start = base[b], n = csum[b];
    cnt[t] = 0;
    __syncthreads();
    for (int i = t; i < n; i += 256)
        atomicAdd(&cnt[(tmp[start + i] >> 16) & 255], 1);
    __syncthreads();
    int v = cnt[t];
    pos[t] = v;
    __syncthreads();
    for (int d = 1; d < 256; d <<= 1) {
        int add = (t >= d) ? pos[t - d] : 0;
        __syncthreads();
        pos[t] += add;
        __syncthreads();
    }
    int excl = pos[t] - v;
    __syncthreads();
    pos[t] = excl;
    __syncthreads();
    for (int i = t; i < n; i += 256) {
        unsigned w = tmp[start + i];
        int p = atomicAdd(&pos[(w >> 16) & 255], 1);   // LDS only
        sedge[start + p] = w;                          // confined to bucket region
    }
}

// --- MFMA edge kernel v16: r15 structure (1-wave blocks, TA-coalesced staging,
//     LDS-atomic segmented max) with perm-fused bf16 packing (bit-exact,
//     -33% pack VALU). ---
__global__ __launch_bounds__(64, 2) void edge_kernel(
    const unsigned* __restrict__ sedge,
    const float* __restrict__ U, const float* __restrict__ V,
    const unsigned short* __restrict__ W2TH, const unsigned short* __restrict__ W2TL,
    const float* __restrict__ b2, float* __restrict__ out) {
    __shared__ char smem[16384];                 // 1 wave, wave-private
    int lane = threadIdx.x & 63;
    char* base = smem;                           // Hhi [0,8K) Hlo [8K,16K)
    char* Hhi = base;
    char* Hlo = base + 8192;
    float* segA = (float*)Hhi;                   // [32 segs][64 cols], overlays Hhi
    float* segB = (float*)Hlo;                   // [32 segs][64 cols], overlays Hlo
    unsigned* edlds = (unsigned*)Hhi;            // 64 u32 edge words, overlays Hhi;
                                                 // fully consumed before convert writes
    int l15 = lane & 15, l4 = lane >> 4;

    float bias = b2[lane];                       // lane = output column

    bf16x8 Bh[2][4], Bl[2][4];
#pragma unroll
    for (int kt = 0; kt < 2; ++kt)
#pragma unroll
        for (int nt = 0; nt < 4; ++nt) {
            int off = (nt * 16 + l15) * 64 + kt * 32 + l4 * 8;
            Bh[kt][nt] = *(const bf16x8*)(W2TH + off);
            Bl[kt][nt] = *(const bf16x8*)(W2TL + off);
        }

    // XCD-chunked swizzle: 2048 blocks, 8 XCDs -> contiguous 256-block chunks
    int bid = blockIdx.x;
    int wid = (bid & 7) * 256 + (bid >> 3);      // 2048 waves (1/block)
    const int NB = NE / 64;                      // 12500 batches
    int bstart = (int)(((long long)wid * NB) >> 11);
    int bend   = (int)(((long long)(wid + 1) * NB) >> 11);

    float run = -3.402823e38f;
    int   segdst = -1;
    bool  firstflush = true;

    int jj = lane & 15;                          // float4 chunk within row
    int rsub = lane >> 4;                        // row sub-index within group of 4

    for (int b = bstart; b < bend; ++b) {
        int e = b * 64 + lane;
        unsigned pe = sedge[e];
        int dst = (int)(pe >> 16);

        // ---- publish edge words to LDS; read all 16 row descriptors up-front
        edlds[lane] = pe;
        unsigned pr[16];
#pragma unroll
        for (int q = 0; q < 16; ++q) pr[q] = edlds[4 * q + rsub];

        // ---- coalesced staging: 16 lanes/row, 4 rows per load instruction;
        //      two halves of 8+8 batched loads, then convert+LDS write
#pragma unroll
        for (int h = 0; h < 2; ++h) {
            float4 uu[8], vv[8];
#pragma unroll
            for (int q = 0; q < 8; ++q) {
                unsigned p = pr[8 * h + q];
                int sr = (int)(p & 0xffffu);
                int dr = (int)(p >> 16);
                uu[q] = *(const float4*)(U + (size_t)dr * F + 4 * jj);
                vv[q] = *(const float4*)(V + (size_t)sr * F + 4 * jj);
            }
#pragma unroll
            for (int q = 0; q < 8; ++q) {
                int r = 32 * h + 4 * q + rsub;
                float4 ua = uu[q], va = vv[q];
                unsigned hw0, hw1, lw0, lw1;
                pack4(relu_f(ua.x + va.x), relu_f(ua.y + va.y),
                      relu_f(ua.z + va.z), relu_f(ua.w + va.w), hw0, hw1, lw0, lw1);
                int g = jj >> 1;
                int byt = r * 128 + ((g ^ (r & 7)) << 4) + (jj & 1) * 8;
                *(uint2*)(Hhi + byt) = make_uint2(hw0, hw1);
                *(uint2*)(Hlo + byt) = make_uint2(lw0, lw1);
            }
        }

        int pdst = __shfl_up(dst, 1, 64);
        bool leader = (lane == 0) || (pdst != dst);
        unsigned long long lead_mask = __ballot(leader);
        unsigned leadlo = (unsigned)lead_mask;
        unsigned leadhi = (unsigned)(lead_mask >> 32);
        int contB = (leadhi & 1u) ? 0 : 1;       // hi half starts with a continuation?

        // ---- MFMA
        f32x4 acc[4][4];
#pragma unroll
        for (int mt = 0; mt < 4; ++mt)
#pragma unroll
            for (int nt = 0; nt < 4; ++nt)
                acc[mt][nt] = (f32x4){0.f, 0.f, 0.f, 0.f};
#pragma unroll
        for (int mt = 0; mt < 4; ++mt) {
            int arow = mt * 16 + l15;
            int abase = arow * 128;
            int am = arow & 7;
            bf16x8 Ah0 = *(const bf16x8*)(Hhi + abase + (((0 + l4) ^ am) << 4));
            bf16x8 Ah1 = *(const bf16x8*)(Hhi + abase + (((4 + l4) ^ am) << 4));
            bf16x8 Al0 = *(const bf16x8*)(Hlo + abase + (((0 + l4) ^ am) << 4));
            bf16x8 Al1 = *(const bf16x8*)(Hlo + abase + (((4 + l4) ^ am) << 4));
#pragma unroll
            for (int nt = 0; nt < 4; ++nt) {
                f32x4 a = acc[mt][nt];
                a = __builtin_amdgcn_mfma_f32_16x16x32_bf16(Ah0, Bh[0][nt], a, 0, 0, 0);
                a = __builtin_amdgcn_mfma_f32_16x16x32_bf16(Ah1, Bh[1][nt], a, 0, 0, 0);
                a = __builtin_amdgcn_mfma_f32_16x16x32_bf16(Al0, Bh[0][nt], a, 0, 0, 0);
                a = __builtin_amdgcn_mfma_f32_16x16x32_bf16(Al1, Bh[1][nt], a, 0, 0, 0);
                a = __builtin_amdgcn_mfma_f32_16x16x32_bf16(Ah0, Bl[0][nt], a, 0, 0, 0);
                a = __builtin_amdgcn_mfma_f32_16x16x32_bf16(Ah1, Bl[1][nt], a, 0, 0, 0);
                acc[mt][nt] = a;
            }
        }
        // staging data in Hhi/Hlo is fully consumed by the ds_reads above;
        // segbufA/segbufB reuse the space (same-wave LDS ops are in-order).

        // ---- segmented-max scatter via LDS float-max atomics
        int usedA = __popc(leadlo);              // bit0 always set
        int usedB = __popc(leadhi) + contB;
        for (int s = 0; s < usedA; ++s) segA[s * 64 + lane] = -3.402823e38f;
        for (int s = 0; s < usedB; ++s) segB[s * 64 + lane] = -3.402823e38f;

        int sid[4][4];                           // segment id of each held row
#pragma unroll
        for (int mt = 0; mt < 4; ++mt)
#pragma unroll
            for (int r = 0; r < 4; ++r) {
                int row = mt * 16 + l4 * 4 + r;
                // INCLUSIVE prefix - 1: leader row and followers agree on id
                sid[mt][r] = (row < 32)
                    ? __popc(leadlo & ((2u << row) - 1u)) - 1
                    : __popc(leadhi & ((2u << (row - 32)) - 1u)) - 1 + contB;
            }

#pragma unroll
        for (int mt = 0; mt < 4; ++mt)
#pragma unroll
            for (int nt = 0; nt < 4; ++nt)
#pragma unroll
                for (int r = 0; r < 4; ++r) {
                    float* sb = (mt < 2) ? segA : segB;
                    (void)__hip_atomic_fetch_max(
                        &sb[sid[mt][r] * 64 + nt * 16 + l15], acc[mt][nt][r],
                        __ATOMIC_RELAXED, __HIP_MEMORY_SCOPE_WAVEFRONT);
                }

        // ---- flush: walk segments (~4) with cross-batch carry
        unsigned mA = leadlo;
        for (int s = 0; s < usedA; ++s) {
            int rb = __ffs(mA) - 1; mA &= mA - 1u;
            int dsts = __shfl(dst, rb, 64);
            float val = segA[s * 64 + lane];
            if (dsts != segdst) {
                if (segdst >= 0) {
                    float v = fmaxf(run + bias, 0.f);
                    if (firstflush) {
                        if (v > 0.f)
                            atomicMax((int*)(out + (size_t)segdst * F + lane),
                                      __float_as_int(v));
                        firstflush = false;
                    } else {
                        out[(size_t)segdst * F + lane] = v;
                    }
                }
                segdst = dsts; run = val;
            } else run = fmaxf(run, val);
        }
        int dst32 = __shfl(dst, 32, 64);
        unsigned mB = leadhi;
        for (int s = 0; s < usedB; ++s) {
            int dsts;
            if (s == 0 && contB) dsts = dst32;   // boundary continuation
            else { int rb = __ffs(mB) - 1; mB &= mB - 1u; dsts = __shfl(dst, 32 + rb, 64); }
            float val = segB[s * 64 + lane];
            if (dsts != segdst) {
                if (segdst >= 0) {
                    float v = fmaxf(run + bias, 0.f);
                    if (firstflush) {
                        if (v > 0.f)
                            atomicMax((int*)(out + (size_t)segdst * F + lane),
                                      __float_as_int(v));
                        firstflush = false;
                    } else {
                        out[(size_t)segdst * F + lane] = v;
                    }
                }
                segdst = dsts; run = val;
            } else run = fmaxf(run, val);
        }
    }
    if (segdst >= 0) {   // final segment may extend into next range -> atomic
        float val = fmaxf(run + bias, 0.f);
        if (val > 0.f)
            atomicMax((int*)(out + (size_t)segdst * F + lane), __float_as_int(val));
    }
}

extern "C" void kernel_launch(void* const* d_in, const int* in_sizes, int n_in,
                              void* d_out, int out_size, void* d_ws, size_t ws_size,
                              hipStream_t stream) {
    const float* x  = (const float*)d_in[0];
    const int*   ei = (const int*)d_in[1];
    const float* W1 = (const float*)d_in[2];
    const float* b1 = (const float*)d_in[3];
    const float* W2 = (const float*)d_in[4];
    const float* b2 = (const float*)d_in[5];
    float* out = (float*)d_out;

    char* ws = (char*)d_ws;
    int*            flag   = (int*)(ws + WS_FLAG);
    unsigned short* WCTH   = (unsigned short*)(ws + WS_WCTH);
    unsigned short* WCTL   = (unsigned short*)(ws + WS_WCTL);
    unsigned short* W2TH   = (unsigned short*)(ws + WS_W2TH);
    unsigned short* W2TL   = (unsigned short*)(ws + WS_W2TL);
    unsigned*       sedge  = (unsigned*)(ws + WS_SEDGE);
    float*          Ubuf   = (float*)(ws + WS_U);
    float*          Vbuf   = (float*)(ws + WS_V);
    int*            bhistT = (int*)(ws + WS_BHT);
    int*            boffT  = (int*)(ws + WS_BOT);
    int*            csum   = (int*)(ws + WS_CSUM);
    int*            baseb  = (int*)(ws + WS_BASE);
    unsigned*       tmp    = (unsigned*)(ws + WS_TMP);

    hipMemsetAsync(flag, 0, 4, stream);
    detect_kernel<<<16, 256, 0, stream>>>(ei, flag);
    prep_kernel<<<48, 256, 0, stream>>>(W1, W2, WCTH, WCTL, W2TH, W2TL);
    histA_kernel<<<256, 256, 0, stream>>>(ei, flag, bhistT);
    scanCols_kernel<<<NBKT, 256, 0, stream>>>(bhistT, boffT, csum);
    scanBase_kernel<<<1, 256, 0, stream>>>(csum, baseb);
    scatterA2_kernel<<<256, 256, 0, stream>>>(ei, flag, boffT, baseb, tmp);
    sortC_kernel<<<NBKT, 256, 0, stream>>>(tmp, baseb, csum, sedge);

    const float* xin = x;
    for (int l = 0; l < 3; ++l) {
        gemm_mfma<<<391, 256, 0, stream>>>(xin, WCTH + l * 8192, WCTL + l * 8192,
                                           b1 + l * 64, Ubuf, Vbuf);
        hipMemsetAsync(out, 0, (size_t)NN * F * sizeof(float), stream);
        edge_kernel<<<2048, 64, 0, stream>>>(sedge, Ubuf, Vbuf,
                                             W2TH + l * 4096, W2TL + l * 4096,
                                             b2 + l * 64, out);
        xin = out;
    }
}

// Round 17
// 250.444 us; speedup vs baseline: 1.0297x; 1.0297x over previous
//
#include <hip/hip_runtime.h>

#define NN 50000
#define NE 800000
#define F  64
#define NBKT 196              // dst>>8 buckets (max dst 49999 -> 195)
#define CHUNK (NE / 256)      // 3125 edges per sort block

typedef __attribute__((ext_vector_type(8))) short bf16x8;
typedef __attribute__((ext_vector_type(4))) float f32x4;

// ---- workspace layout (bytes), 256-aligned ----
#define WS_FLAG   0u
#define WS_WCTH   256u        // 3*128*64 u16: [A|B]^T hi    -> 49408
#define WS_WCTL   49408u      // 3*128*64 u16: [A|B]^T lo    -> 98560
#define WS_W2TH   98560u      // 3*4096 u16 (bf16 hi of W2T) -> 123136
#define WS_W2TL   123136u     // 3*4096 u16 (bf16 lo of W2T) -> 147712
#define WS_SEDGE  147712u     // NE u32 packed (dst<<16)|src -> 3347712
#define WS_U      3347712u    // NN*F f32                    -> 16147712
#define WS_V      16147712u   // NN*F f32                    -> 28947712
// sort scratch aliased inside U/V (sort completes before first gemm writes them)
#define WS_BHT    (WS_U + 0u)        // NBKT*256 int (transposed block hists)
#define WS_BOT    (WS_U + 200960u)   // NBKT*256 int (per-block bucket offsets)
#define WS_CSUM   (WS_U + 401920u)   // NBKT int (bucket totals)
#define WS_BASE   (WS_U + 402944u)   // NBKT int (bucket bases)
#define WS_TMP    (WS_V + 0u)        // NE u32  coarse-bucketed edges

__device__ __forceinline__ float relu_f(float a) { return a > 0.f ? a : 0.f; }

// pack 4 floats into 2 hi-bf16 words + 2 lo-bf16 words
__device__ __forceinline__ void pack4(float f0, float f1, float f2, float f3,
                                      unsigned& hw0, unsigned& hw1,
                                      unsigned& lw0, unsigned& lw1) {
    unsigned u0 = __float_as_uint(f0), u1 = __float_as_uint(f1);
    unsigned u2 = __float_as_uint(f2), u3 = __float_as_uint(f3);
    unsigned h0 = u0 & 0xffff0000u, h1 = u1 & 0xffff0000u;
    unsigned h2 = u2 & 0xffff0000u, h3 = u3 & 0xffff0000u;
    float l0 = f0 - __uint_as_float(h0), l1 = f1 - __uint_as_float(h1);
    float l2 = f2 - __uint_as_float(h2), l3 = f3 - __uint_as_float(h3);
    hw0 = h1 | (h0 >> 16);
    hw1 = h3 | (h2 >> 16);
    lw0 = (__float_as_uint(l1) & 0xffff0000u) | (__float_as_uint(l0) >> 16);
    lw1 = (__float_as_uint(l3) & 0xffff0000u) | (__float_as_uint(l2) >> 16);
}

// --- detect idx payload: int64 (odd words all zero) vs int32 ---
__global__ void detect_kernel(const int* __restrict__ idx, int* __restrict__ flag) {
    int t = blockIdx.x * blockDim.x + threadIdx.x;   // 4096 samples
    if (idx[2 * t + 1] != 0) atomicOr(flag, 1);      // 1 -> int32 layout
}

// --- build transposed hi/lo bf16 splits: WC = [A|B] (A = W1a - W1b, B = W1b), W2T ---
__global__ void prep_kernel(const float* __restrict__ W1, const float* __restrict__ W2,
                            unsigned short* __restrict__ WCTH, unsigned short* __restrict__ WCTL,
                            unsigned short* __restrict__ W2TH, unsigned short* __restrict__ W2TL) {
    int i = blockIdx.x * blockDim.x + threadIdx.x;   // 0 .. 3*4096-1
    int l = i >> 12;
    int r = i & 4095;
    int k = r >> 6;
    int j = r & 63;
    float wa = W1[l * 8192 + k * 64 + j];
    float wb = W1[l * 8192 + 4096 + k * 64 + j];
    float a = wa - wb;
    unsigned ua = __float_as_uint(a), ahi = ua & 0xffff0000u;
    float alo = a - __uint_as_float(ahi);
    WCTH[l * 8192 + j * 64 + k] = (unsigned short)(ahi >> 16);
    WCTL[l * 8192 + j * 64 + k] = (unsigned short)(__float_as_uint(alo) >> 16);
    unsigned ub = __float_as_uint(wb), bhi = ub & 0xffff0000u;
    float blo = wb - __uint_as_float(bhi);
    WCTH[l * 8192 + (64 + j) * 64 + k] = (unsigned short)(bhi >> 16);
    WCTL[l * 8192 + (64 + j) * 64 + k] = (unsigned short)(__float_as_uint(blo) >> 16);
    float w = W2[l * 4096 + k * 64 + j];
    unsigned uw = __float_as_uint(w), whi = uw & 0xffff0000u;
    float wlo = w - __uint_as_float(whi);
    W2TH[l * 4096 + j * 64 + k] = (unsigned short)(whi >> 16);
    W2TL[l * 4096 + j * 64 + k] = (unsigned short)(__float_as_uint(wlo) >> 16);
}

// --- MFMA gemm: [U|V] = x @ [A|B] (+b1 on U). Wave = (64-node batch) x (U or V half). ---
__global__ __launch_bounds__(256, 2) void gemm_mfma(
    const float* __restrict__ xin,
    const unsigned short* __restrict__ WCTH, const unsigned short* __restrict__ WCTL,
    const float* __restrict__ b1,
    float* __restrict__ U, float* __restrict__ V) {
    __shared__ char smem[65536];                 // 4 waves x 16 KB, wave-private
    int lane = threadIdx.x & 63;
    int wib  = threadIdx.x >> 6;
    char* base = smem + wib * 16384;
    char* Hhi = base;
    char* Hlo = base + 8192;
    int l15 = lane & 15, l4 = lane >> 4;

    int wid = blockIdx.x * 4 + wib;              // 1564 waves exactly
    int b = wid >> 1;                            // node batch (0..781)
    int half = wid & 1;                          // 0 -> U, 1 -> V

    bf16x8 Bh[2][4], Bl[2][4];
#pragma unroll
    for (int kt = 0; kt < 2; ++kt)
#pragma unroll
        for (int nt = 0; nt < 4; ++nt) {
            int off = (half * 64 + nt * 16 + l15) * 64 + kt * 32 + l4 * 8;
            Bh[kt][nt] = *(const bf16x8*)(WCTH + off);
            Bl[kt][nt] = *(const bf16x8*)(WCTL + off);
        }

    int jj = lane & 15;                          // float4 chunk within row
    int rsub = lane >> 4;                        // row sub-index within group of 4
#pragma unroll
    for (int i = 0; i < 16; ++i) {
        int r = 4 * i + rsub;
        int node = b * 64 + r;
        int cnode = node < NN ? node : NN - 1;
        float4 xv = *(const float4*)(xin + (size_t)cnode * F + 4 * jj);
        unsigned hw0, hw1, lw0, lw1;
        pack4(xv.x, xv.y, xv.z, xv.w, hw0, hw1, lw0, lw1);
        int g = jj >> 1;
        int byt = r * 128 + ((g ^ (r & 7)) << 4) + (jj & 1) * 8;
        *(uint2*)(Hhi + byt) = make_uint2(hw0, hw1);
        *(uint2*)(Hlo + byt) = make_uint2(lw0, lw1);
    }

    f32x4 acc[4][4];
#pragma unroll
    for (int mt = 0; mt < 4; ++mt)
#pragma unroll
        for (int nt = 0; nt < 4; ++nt)
            acc[mt][nt] = (f32x4){0.f, 0.f, 0.f, 0.f};
#pragma unroll
    for (int mt = 0; mt < 4; ++mt) {
        int arow = mt * 16 + l15;
        int abase = arow * 128;
        int am = arow & 7;
        bf16x8 Ah0 = *(const bf16x8*)(Hhi + abase + (((0 + l4) ^ am) << 4));
        bf16x8 Ah1 = *(const bf16x8*)(Hhi + abase + (((4 + l4) ^ am) << 4));
        bf16x8 Al0 = *(const bf16x8*)(Hlo + abase + (((0 + l4) ^ am) << 4));
        bf16x8 Al1 = *(const bf16x8*)(Hlo + abase + (((4 + l4) ^ am) << 4));
#pragma unroll
        for (int nt = 0; nt < 4; ++nt) {
            f32x4 a = acc[mt][nt];
            a = __builtin_amdgcn_mfma_f32_16x16x32_bf16(Ah0, Bh[0][nt], a, 0, 0, 0);
            a = __builtin_amdgcn_mfma_f32_16x16x32_bf16(Ah1, Bh[1][nt], a, 0, 0, 0);
            a = __builtin_amdgcn_mfma_f32_16x16x32_bf16(Al0, Bh[0][nt], a, 0, 0, 0);
            a = __builtin_amdgcn_mfma_f32_16x16x32_bf16(Al1, Bh[1][nt], a, 0, 0, 0);
            a = __builtin_amdgcn_mfma_f32_16x16x32_bf16(Ah0, Bl[0][nt], a, 0, 0, 0);
            a = __builtin_amdgcn_mfma_f32_16x16x32_bf16(Ah1, Bl[1][nt], a, 0, 0, 0);
            acc[mt][nt] = a;
        }
    }

    float bc[4];
#pragma unroll
    for (int nt = 0; nt < 4; ++nt)
        bc[nt] = (half == 0) ? b1[nt * 16 + l15] : 0.f;
    float* outp = (half == 0) ? U : V;
#pragma unroll
    for (int mt = 0; mt < 4; ++mt)
#pragma unroll
        for (int nt = 0; nt < 4; ++nt) {
            int col = nt * 16 + l15;
#pragma unroll
            for (int r = 0; r < 4; ++r) {
                int row = b * 64 + mt * 16 + l4 * 4 + r;
                if (row < NN) outp[(size_t)row * F + col] = acc[mt][nt][r] + bc[nt];
            }
        }
}

// --- deterministic split-sort by dst: NO global atomics anywhere ---
__global__ __launch_bounds__(256) void histA_kernel(const int* __restrict__ idx,
                                                    const int* __restrict__ flag,
                                                    int* __restrict__ bhistT) {
    __shared__ int h[NBKT];
    int tid = threadIdx.x, blk = blockIdx.x;
    if (tid < NBKT) h[tid] = 0;
    __syncthreads();
    int fl = *flag;
    int start = blk * CHUNK;
    for (int i = tid; i < CHUNK; i += 256) {
        int e = start + i;
        int dst = fl ? idx[NE + e] : idx[2 * NE + 2 * e];
        atomicAdd(&h[dst >> 8], 1);
    }
    __syncthreads();
    if (tid < NBKT) bhistT[tid * 256 + blk] = h[tid];
}

__global__ __launch_bounds__(256) void scanCols_kernel(const int* __restrict__ bhistT,
                                                       int* __restrict__ boffT,
                                                       int* __restrict__ csum) {
    __shared__ int buf[256];
    int t = threadIdx.x, b = blockIdx.x;
    int v = bhistT[b * 256 + t];
    buf[t] = v;
    __syncthreads();
    for (int d = 1; d < 256; d <<= 1) {
        int add = (t >= d) ? buf[t - d] : 0;
        __syncthreads();
        buf[t] += add;
        __syncthreads();
    }
    boffT[b * 256 + t] = buf[t] - v;
    if (t == 255) csum[b] = buf[255];
}

__global__ __launch_bounds__(256) void scanBase_kernel(const int* __restrict__ csum,
                                                       int* __restrict__ base) {
    __shared__ int buf[256];
    int t = threadIdx.x;
    int v = (t < NBKT) ? csum[t] : 0;
    buf[t] = v;
    __syncthreads();
    for (int d = 1; d < 256; d <<= 1) {
        int add = (t >= d) ? buf[t - d] : 0;
        __syncthreads();
        buf[t] += add;
        __syncthreads();
    }
    if (t < NBKT) base[t] = buf[t] - v;
}

__global__ __launch_bounds__(256) void scatterA2_kernel(const int* __restrict__ idx,
                                                        const int* __restrict__ flag,
                                                        const int* __restrict__ boffT,
                                                        const int* __restrict__ base,
                                                        unsigned* __restrict__ tmp) {
    __shared__ int loc[NBKT];
    __shared__ int bb[NBKT];
    int tid = threadIdx.x, blk = blockIdx.x;
    if (tid < NBKT) { loc[tid] = 0; bb[tid] = base[tid] + boffT[tid * 256 + blk]; }
    __syncthreads();
    int fl = *flag;
    int start = blk * CHUNK;
    for (int i = tid; i < CHUNK; i += 256) {
        int e = start + i;
        int src, dst;
        if (fl) { src = idx[e];     dst = idx[NE + e]; }
        else    { src = idx[2 * e]; dst = idx[2 * NE + 2 * e]; }
        int bkt = dst >> 8;
        int my = atomicAdd(&loc[bkt], 1);          // LDS only
        tmp[bb[bkt] + my] = ((unsigned)dst << 16) | (unsigned)src;
    }
}

__global__ __launch_bounds__(256) void sortC_kernel(const unsigned* __restrict__ tmp,
                                                    const int* __restrict__ base,
                                                    const int* __restrict__ csum,
                                                    unsigned* __restrict__ sedge) {
    __shared__ int cnt[256];
    __shared__ int pos[256];
    int b = blockIdx.x, t = threadIdx.x;
    int start = base[b], n = csum[b];
    cnt[t] = 0;
    __syncthreads();
    for (int i = t; i < n; i += 256)
        atomicAdd(&cnt[(tmp[start + i] >> 16) & 255], 1);
    __syncthreads();
    int v = cnt[t];
    pos[t] = v;
    __syncthreads();
    for (int d = 1; d < 256; d <<= 1) {
        int add = (t >= d) ? pos[t - d] : 0;
        __syncthreads();
        pos[t] += add;
        __syncthreads();
    }
    int excl = pos[t] - v;
    __syncthreads();
    pos[t] = excl;
    __syncthreads();
    for (int i = t; i < n; i += 256) {
        unsigned w = tmp[start + i];
        int p = atomicAdd(&pos[(w >> 16) & 255], 1);   // LDS only
        sedge[start + p] = w;                          // confined to bucket region
    }
}

// --- MFMA edge kernel (best, r15): 1-wave blocks (64 threads, 16 KB LDS ->
//     10 waves/CU), TA-coalesced staging (16 lanes/row, 4 rows/instruction,
//     edge descriptors via LDS broadcast), LDS-atomic segmented max (no serial
//     carry chain), XCD-chunked block swizzle. ---
__global__ __launch_bounds__(64, 2) void edge_kernel(
    const unsigned* __restrict__ sedge,
    const float* __restrict__ U, const float* __restrict__ V,
    const unsigned short* __restrict__ W2TH, const unsigned short* __restrict__ W2TL,
    const float* __restrict__ b2, float* __restrict__ out) {
    __shared__ char smem[16384];                 // 1 wave, wave-private
    int lane = threadIdx.x & 63;
    char* base = smem;                           // Hhi [0,8K) Hlo [8K,16K)
    char* Hhi = base;
    char* Hlo = base + 8192;
    float* segA = (float*)Hhi;                   // [32 segs][64 cols], overlays Hhi
    float* segB = (float*)Hlo;                   // [32 segs][64 cols], overlays Hlo
    unsigned* edlds = (unsigned*)Hhi;            // 64 u32 edge words, overlays Hhi;
                                                 // fully consumed before convert writes
    int l15 = lane & 15, l4 = lane >> 4;

    float bias = b2[lane];                       // lane = output column

    bf16x8 Bh[2][4], Bl[2][4];
#pragma unroll
    for (int kt = 0; kt < 2; ++kt)
#pragma unroll
        for (int nt = 0; nt < 4; ++nt) {
            int off = (nt * 16 + l15) * 64 + kt * 32 + l4 * 8;
            Bh[kt][nt] = *(const bf16x8*)(W2TH + off);
            Bl[kt][nt] = *(const bf16x8*)(W2TL + off);
        }

    // XCD-chunked swizzle: 2048 blocks, 8 XCDs -> contiguous 256-block chunks
    int bid = blockIdx.x;
    int wid = (bid & 7) * 256 + (bid >> 3);      // 2048 waves (1/block)
    const int NB = NE / 64;                      // 12500 batches
    int bstart = (int)(((long long)wid * NB) >> 11);
    int bend   = (int)(((long long)(wid + 1) * NB) >> 11);

    float run = -3.402823e38f;
    int   segdst = -1;
    bool  firstflush = true;

    int jj = lane & 15;                          // float4 chunk within row
    int rsub = lane >> 4;                        // row sub-index within group of 4

    for (int b = bstart; b < bend; ++b) {
        int e = b * 64 + lane;
        unsigned pe = sedge[e];
        int dst = (int)(pe >> 16);

        // ---- publish edge words to LDS; read all 16 row descriptors up-front
        edlds[lane] = pe;
        unsigned pr[16];
#pragma unroll
        for (int q = 0; q < 16; ++q) pr[q] = edlds[4 * q + rsub];

        // ---- coalesced staging: 16 lanes/row, 4 rows per load instruction;
        //      two halves of 8+8 batched loads, then convert+LDS write
#pragma unroll
        for (int h = 0; h < 2; ++h) {
            float4 uu[8], vv[8];
#pragma unroll
            for (int q = 0; q < 8; ++q) {
                unsigned p = pr[8 * h + q];
                int sr = (int)(p & 0xffffu);
                int dr = (int)(p >> 16);
                uu[q] = *(const float4*)(U + (size_t)dr * F + 4 * jj);
                vv[q] = *(const float4*)(V + (size_t)sr * F + 4 * jj);
            }
#pragma unroll
            for (int q = 0; q < 8; ++q) {
                int r = 32 * h + 4 * q + rsub;
                float4 ua = uu[q], va = vv[q];
                unsigned hw0, hw1, lw0, lw1;
                pack4(relu_f(ua.x + va.x), relu_f(ua.y + va.y),
                      relu_f(ua.z + va.z), relu_f(ua.w + va.w), hw0, hw1, lw0, lw1);
                int g = jj >> 1;
                int byt = r * 128 + ((g ^ (r & 7)) << 4) + (jj & 1) * 8;
                *(uint2*)(Hhi + byt) = make_uint2(hw0, hw1);
                *(uint2*)(Hlo + byt) = make_uint2(lw0, lw1);
            }
        }

        int pdst = __shfl_up(dst, 1, 64);
        bool leader = (lane == 0) || (pdst != dst);
        unsigned long long lead_mask = __ballot(leader);
        unsigned leadlo = (unsigned)lead_mask;
        unsigned leadhi = (unsigned)(lead_mask >> 32);
        int contB = (leadhi & 1u) ? 0 : 1;       // hi half starts with a continuation?

        // ---- MFMA
        f32x4 acc[4][4];
#pragma unroll
        for (int mt = 0; mt < 4; ++mt)
#pragma unroll
            for (int nt = 0; nt < 4; ++nt)
                acc[mt][nt] = (f32x4){0.f, 0.f, 0.f, 0.f};
#pragma unroll
        for (int mt = 0; mt < 4; ++mt) {
            int arow = mt * 16 + l15;
            int abase = arow * 128;
            int am = arow & 7;
            bf16x8 Ah0 = *(const bf16x8*)(Hhi + abase + (((0 + l4) ^ am) << 4));
            bf16x8 Ah1 = *(const bf16x8*)(Hhi + abase + (((4 + l4) ^ am) << 4));
            bf16x8 Al0 = *(const bf16x8*)(Hlo + abase + (((0 + l4) ^ am) << 4));
            bf16x8 Al1 = *(const bf16x8*)(Hlo + abase + (((4 + l4) ^ am) << 4));
#pragma unroll
            for (int nt = 0; nt < 4; ++nt) {
                f32x4 a = acc[mt][nt];
                a = __builtin_amdgcn_mfma_f32_16x16x32_bf16(Ah0, Bh[0][nt], a, 0, 0, 0);
                a = __builtin_amdgcn_mfma_f32_16x16x32_bf16(Ah1, Bh[1][nt], a, 0, 0, 0);
                a = __builtin_amdgcn_mfma_f32_16x16x32_bf16(Al0, Bh[0][nt], a, 0, 0, 0);
                a = __builtin_amdgcn_mfma_f32_16x16x32_bf16(Al1, Bh[1][nt], a, 0, 0, 0);
                a = __builtin_amdgcn_mfma_f32_16x16x32_bf16(Ah0, Bl[0][nt], a, 0, 0, 0);
                a = __builtin_amdgcn_mfma_f32_16x16x32_bf16(Ah1, Bl[1][nt], a, 0, 0, 0);
                acc[mt][nt] = a;
            }
        }
        // staging data in Hhi/Hlo is fully consumed by the ds_reads above;
        // segbufA/segbufB reuse the space (same-wave LDS ops are in-order).

        // ---- segmented-max scatter via LDS float-max atomics
        int usedA = __popc(leadlo);              // bit0 always set
        int usedB = __popc(leadhi) + contB;
        for (int s = 0; s < usedA; ++s) segA[s * 64 + lane] = -3.402823e38f;
        for (int s = 0; s < usedB; ++s) segB[s * 64 + lane] = -3.402823e38f;

        int sid[4][4];                           // segment id of each held row
#pragma unroll
        for (int mt = 0; mt < 4; ++mt)
#pragma unroll
            for (int r = 0; r < 4; ++r) {
                int row = mt * 16 + l4 * 4 + r;
                // INCLUSIVE prefix - 1: leader row and followers agree on id
                sid[mt][r] = (row < 32)
                    ? __popc(leadlo & ((2u << row) - 1u)) - 1
                    : __popc(leadhi & ((2u << (row - 32)) - 1u)) - 1 + contB;
            }

#pragma unroll
        for (int mt = 0; mt < 4; ++mt)
#pragma unroll
            for (int nt = 0; nt < 4; ++nt)
#pragma unroll
                for (int r = 0; r < 4; ++r) {
                    float* sb = (mt < 2) ? segA : segB;
                    (void)__hip_atomic_fetch_max(
                        &sb[sid[mt][r] * 64 + nt * 16 + l15], acc[mt][nt][r],
                        __ATOMIC_RELAXED, __HIP_MEMORY_SCOPE_WAVEFRONT);
                }

        // ---- flush: walk segments (~4) with cross-batch carry
        unsigned mA = leadlo;
        for (int s = 0; s < usedA; ++s) {
            int rb = __ffs(mA) - 1; mA &= mA - 1u;
            int dsts = __shfl(dst, rb, 64);
            float val = segA[s * 64 + lane];
            if (dsts != segdst) {
                if (segdst >= 0) {
                    float v = fmaxf(run + bias, 0.f);
                    if (firstflush) {
                        if (v > 0.f)
                            atomicMax((int*)(out + (size_t)segdst * F + lane),
                                      __float_as_int(v));
                        firstflush = false;
                    } else {
                        out[(size_t)segdst * F + lane] = v;
                    }
                }
                segdst = dsts; run = val;
            } else run = fmaxf(run, val);
        }
        int dst32 = __shfl(dst, 32, 64);
        unsigned mB = leadhi;
        for (int s = 0; s < usedB; ++s) {
            int dsts;
            if (s == 0 && contB) dsts = dst32;   // boundary continuation
            else { int rb = __ffs(mB) - 1; mB &= mB - 1u; dsts = __shfl(dst, 32 + rb, 64); }
            float val = segB[s * 64 + lane];
            if (dsts != segdst) {
                if (segdst >= 0) {
                    float v = fmaxf(run + bias, 0.f);
                    if (firstflush) {
                        if (v > 0.f)
                            atomicMax((int*)(out + (size_t)segdst * F + lane),
                                      __float_as_int(v));
                        firstflush = false;
                    } else {
                        out[(size_t)segdst * F + lane] = v;
                    }
                }
                segdst = dsts; run = val;
            } else run = fmaxf(run, val);
        }
    }
    if (segdst >= 0) {   // final segment may extend into next range -> atomic
        float val = fmaxf(run + bias, 0.f);
        if (val > 0.f)
            atomicMax((int*)(out + (size_t)segdst * F + lane), __float_as_int(val));
    }
}

extern "C" void kernel_launch(void* const* d_in, const int* in_sizes, int n_in,
                              void* d_out, int out_size, void* d_ws, size_t ws_size,
                              hipStream_t stream) {
    const float* x  = (const float*)d_in[0];
    const int*   ei = (const int*)d_in[1];
    const float* W1 = (const float*)d_in[2];
    const float* b1 = (const float*)d_in[3];
    const float* W2 = (const float*)d_in[4];
    const float* b2 = (const float*)d_in[5];
    float* out = (float*)d_out;

    char* ws = (char*)d_ws;
    int*            flag   = (int*)(ws + WS_FLAG);
    unsigned short* WCTH   = (unsigned short*)(ws + WS_WCTH);
    unsigned short* WCTL   = (unsigned short*)(ws + WS_WCTL);
    unsigned short* W2TH   = (unsigned short*)(ws + WS_W2TH);
    unsigned short* W2TL   = (unsigned short*)(ws + WS_W2TL);
    unsigned*       sedge  = (unsigned*)(ws + WS_SEDGE);
    float*          Ubuf   = (float*)(ws + WS_U);
    float*          Vbuf   = (float*)(ws + WS_V);
    int*            bhistT = (int*)(ws + WS_BHT);
    int*            boffT  = (int*)(ws + WS_BOT);
    int*            csum   = (int*)(ws + WS_CSUM);
    int*            baseb  = (int*)(ws + WS_BASE);
    unsigned*       tmp    = (unsigned*)(ws + WS_TMP);

    hipMemsetAsync(flag, 0, 4, stream);
    detect_kernel<<<16, 256, 0, stream>>>(ei, flag);
    prep_kernel<<<48, 256, 0, stream>>>(W1, W2, WCTH, WCTL, W2TH, W2TL);
    histA_kernel<<<256, 256, 0, stream>>>(ei, flag, bhistT);
    scanCols_kernel<<<NBKT, 256, 0, stream>>>(bhistT, boffT, csum);
    scanBase_kernel<<<1, 256, 0, stream>>>(csum, baseb);
    scatterA2_kernel<<<256, 256, 0, stream>>>(ei, flag, boffT, baseb, tmp);
    sortC_kernel<<<NBKT, 256, 0, stream>>>(tmp, baseb, csum, sedge);

    const float* xin = x;
    for (int l = 0; l < 3; ++l) {
        gemm_mfma<<<391, 256, 0, stream>>>(xin, WCTH + l * 8192, WCTL + l * 8192,
                                           b1 + l * 64, Ubuf, Vbuf);
        hipMemsetAsync(out, 0, (size_t)NN * F * sizeof(float), stream);
        edge_kernel<<<2048, 64, 0, stream>>>(sedge, Ubuf, Vbuf,
                                             W2TH + l * 4096, W2TL + l * 4096,
                                             b2 + l * 64, out);
        xin = out;
    }
}